// Round 1
// baseline (1094.897 us; speedup 1.0000x reference)
//
#include <hip/hip_runtime.h>
#include <math.h>

// ---------------------------------------------------------------------------
// GraphConv (2-layer GAT) pipeline, fp32 baseline.
//  feats = [img@Wi+bi | txt@Wt+bt] -> scatter(ci) -> gelu -> node
//  CSR by dst (count/scan/fill), self loops appended
//  layer l: h = x@Wl ; s_src/s_dst = h@a ; per-dst: out = sum(w*h[src])/sum(w)
//           + bias -> relu (l=0) / gelu (l=1)
// ---------------------------------------------------------------------------

__device__ __forceinline__ float gelu_exact(float x) {
    return 0.5f * x * (1.0f + erff(x * 0.70710678118654752f));
}

#define TILE_M 128
#define TILE_N 128
#define BK 32

// EPI=0: plain store C[row*256 + colt+col]
// EPI=1: gelu(acc+bias[col]) scattered to C[ci[row]*256 + col_base + col]
template<int EPI>
__global__ __launch_bounds__(256)
void gemm_fp32(const float* __restrict__ A, const float* __restrict__ B,
               const float* __restrict__ bias, float* __restrict__ C,
               const int* __restrict__ ci,
               int M, int K, int Bcols, int col_base)
{
    __shared__ float As[TILE_M][BK + 1];
    __shared__ float Bs[BK][TILE_N];
    const int tid = threadIdx.x;
    const int row0 = blockIdx.x * TILE_M;
    const int colt = blockIdx.y * TILE_N;
    const int ty = tid >> 4, tx = tid & 15;

    float acc[8][8];
#pragma unroll
    for (int i = 0; i < 8; i++)
#pragma unroll
        for (int j = 0; j < 8; j++) acc[i][j] = 0.f;

    for (int k0 = 0; k0 < K; k0 += BK) {
        // A tile: 128x32 = 1024 float4, 4 per thread
#pragma unroll
        for (int p = 0; p < 4; p++) {
            int idx = tid + p * 256;
            int r = idx >> 3;
            int c4 = (idx & 7) * 4;
            int gr = row0 + r;
            float4 v = make_float4(0.f, 0.f, 0.f, 0.f);
            if (gr < M) v = *(const float4*)&A[(size_t)gr * K + k0 + c4];
            As[r][c4 + 0] = v.x; As[r][c4 + 1] = v.y;
            As[r][c4 + 2] = v.z; As[r][c4 + 3] = v.w;
        }
        // B tile: 32x128 = 1024 float4, 4 per thread
#pragma unroll
        for (int p = 0; p < 4; p++) {
            int idx = tid + p * 256;
            int r = idx >> 5;
            int c4 = (idx & 31) * 4;
            float4 v = *(const float4*)&B[(size_t)(k0 + r) * Bcols + colt + c4];
            *(float4*)&Bs[r][c4] = v;
        }
        __syncthreads();
#pragma unroll
        for (int kk = 0; kk < BK; kk++) {
            float a[8], b[8];
#pragma unroll
            for (int i = 0; i < 8; i++) a[i] = As[ty * 8 + i][kk];
            float4 b0 = *(float4*)&Bs[kk][tx * 8];
            float4 b1 = *(float4*)&Bs[kk][tx * 8 + 4];
            b[0] = b0.x; b[1] = b0.y; b[2] = b0.z; b[3] = b0.w;
            b[4] = b1.x; b[5] = b1.y; b[6] = b1.z; b[7] = b1.w;
#pragma unroll
            for (int i = 0; i < 8; i++)
#pragma unroll
                for (int j = 0; j < 8; j++) acc[i][j] = fmaf(a[i], b[j], acc[i][j]);
        }
        __syncthreads();
    }

#pragma unroll
    for (int i = 0; i < 8; i++) {
        int gr = row0 + ty * 8 + i;
        if (gr >= M) continue;
        float vals[8];
#pragma unroll
        for (int j = 0; j < 8; j++) {
            int col = colt + tx * 8 + j;
            float v = acc[i][j];
            if (EPI == 1) v = gelu_exact(v + bias[col]);
            vals[j] = v;
        }
        size_t base;
        if (EPI == 1) {
            int r = ci[gr];
            base = (size_t)r * 256 + col_base + colt + tx * 8;
        } else {
            base = (size_t)gr * 256 + colt + tx * 8;
        }
        *(float4*)&C[base]     = make_float4(vals[0], vals[1], vals[2], vals[3]);
        *(float4*)&C[base + 4] = make_float4(vals[4], vals[5], vals[6], vals[7]);
    }
}

// per-node attention scores: s_src[n] = h[n].asrc, s_dst[n] = h[n].adst
__global__ __launch_bounds__(256)
void scores_kernel(const float* __restrict__ h, const float* __restrict__ asrc,
                   const float* __restrict__ adst, float* __restrict__ s_src,
                   float* __restrict__ s_dst, int N)
{
    int wave = threadIdx.x >> 6;
    int lane = threadIdx.x & 63;
    int n = blockIdx.x * 4 + wave;
    if (n >= N) return;
    float4 hv = *(const float4*)&h[(size_t)n * 256 + lane * 4];
    float4 av = *(const float4*)&asrc[lane * 4];
    float4 dv = *(const float4*)&adst[lane * 4];
    float ps = hv.x * av.x + hv.y * av.y + hv.z * av.z + hv.w * av.w;
    float pd = hv.x * dv.x + hv.y * dv.y + hv.z * dv.z + hv.w * dv.w;
#pragma unroll
    for (int off = 32; off; off >>= 1) {
        ps += __shfl_xor(ps, off);
        pd += __shfl_xor(pd, off);
    }
    if (lane == 0) { s_src[n] = ps; s_dst[n] = pd; }
}

// ---- CSR build ----
__global__ void init_cnt(int* cnt, int N) {
    int i = blockIdx.x * 256 + threadIdx.x;
    if (i < N) cnt[i] = 1;   // self loop
}

__global__ void count_edges(const int* __restrict__ edges, int* cnt, int E) {
    int e = blockIdx.x * 256 + threadIdx.x;
    if (e < E) atomicAdd(&cnt[edges[2 * e + 1]], 1);
}

__global__ void scan1(const int* __restrict__ cnt, int* __restrict__ rs,
                      int* __restrict__ bsum, int N)
{
    __shared__ int sm[256];
    int tid = threadIdx.x;
    int i = blockIdx.x * 256 + tid;
    int v = (i < N) ? cnt[i] : 0;
    sm[tid] = v;
    __syncthreads();
    for (int off = 1; off < 256; off <<= 1) {
        int t = (tid >= off) ? sm[tid - off] : 0;
        __syncthreads();
        sm[tid] += t;
        __syncthreads();
    }
    if (i < N) rs[i] = sm[tid] - v;            // exclusive within block
    if (tid == 255) bsum[blockIdx.x] = sm[255];
}

__global__ void scan2(int* bsum, int nb) {
    __shared__ int sm[256];
    int tid = threadIdx.x;
    int v = (tid < nb) ? bsum[tid] : 0;
    sm[tid] = v;
    __syncthreads();
    for (int off = 1; off < 256; off <<= 1) {
        int t = (tid >= off) ? sm[tid - off] : 0;
        __syncthreads();
        sm[tid] += t;
        __syncthreads();
    }
    if (tid < nb) bsum[tid] = sm[tid] - v;     // exclusive
}

__global__ void scan3(int* __restrict__ rs, const int* __restrict__ bsum,
                      int N, int total)
{
    int i = blockIdx.x * 256 + threadIdx.x;
    if (i < N) rs[i] += bsum[i >> 8];
    if (i == 0) rs[N] = total;
}

__global__ void copy_cursor(const int* __restrict__ rs, int* __restrict__ cur, int N) {
    int i = blockIdx.x * 256 + threadIdx.x;
    if (i < N) cur[i] = rs[i];
}

__global__ void fill_csr(const int* __restrict__ edges, int* __restrict__ cur,
                         int* __restrict__ col, int E, int N)
{
    int i = blockIdx.x * 256 + threadIdx.x;
    if (i < E) {
        int s = edges[2 * i], d = edges[2 * i + 1];
        col[atomicAdd(&cur[d], 1)] = s;
    } else if (i < E + N) {
        int n = i - E;
        col[atomicAdd(&cur[n], 1)] = n;        // self loop
    }
}

// per-dst-node attention aggregation. thread t owns output element t.
// EPI=0: relu(v+bias), EPI=1: gelu(v+bias)
template<int EPI>
__global__ __launch_bounds__(256)
void attn_kernel(const float* __restrict__ h, const float* __restrict__ s_src,
                 const float* __restrict__ s_dst, const int* __restrict__ rs,
                 const int* __restrict__ col, const float* __restrict__ bias,
                 float* __restrict__ out, int N)
{
    int n = blockIdx.x;
    int t = threadIdx.x;
    float sd = s_dst[n];
    int beg = rs[n], end = rs[n + 1];
    float acc = 0.f, den = 0.f;
    for (int s = beg; s < end; ++s) {
        int src = col[s];
        float e = s_src[src] + sd;
        e = (e > 0.f) ? e : 0.2f * e;
        float w = expf(e);
        den += w;
        acc = fmaf(w, h[(size_t)src * 256 + t], acc);
    }
    float v = acc / den + bias[t];
    out[(size_t)n * 256 + t] = (EPI == 1) ? gelu_exact(v) : fmaxf(v, 0.f);
}

extern "C" void kernel_launch(void* const* d_in, const int* in_sizes, int n_in,
                              void* d_out, int out_size, void* d_ws, size_t ws_size,
                              hipStream_t stream)
{
    const float* img    = (const float*)d_in[0];
    const float* txt    = (const float*)d_in[1];
    const int*   ci     = (const int*)d_in[2];
    const int*   edges  = (const int*)d_in[3];
    const float* w_img  = (const float*)d_in[4];
    const float* b_img  = (const float*)d_in[5];
    const float* w_text = (const float*)d_in[6];
    const float* b_text = (const float*)d_in[7];
    const float* W0     = (const float*)d_in[8];
    const float* asrc0  = (const float*)d_in[9];
    const float* adst0  = (const float*)d_in[10];
    const float* bias0  = (const float*)d_in[11];
    const float* W1     = (const float*)d_in[12];
    const float* asrc1  = (const float*)d_in[13];
    const float* adst1  = (const float*)d_in[14];
    const float* bias1  = (const float*)d_in[15];

    const int N = in_sizes[2];
    const int E = in_sizes[3] / 2;
    const int T = E + N;                 // total edges incl self loops

    // workspace layout
    float* fA   = (float*)d_ws;                    // node, later h1   N*256
    float* fB   = fA + (size_t)N * 256;            // out0             N*256
    float* sS   = fB + (size_t)N * 256;            // N
    float* sD   = sS + N;                          // N
    int*   rs   = (int*)(sD + N);                  // N+1
    int*   cur  = rs + (N + 1);                    // N
    int*   col  = cur + N;                         // E+N
    int*   bsum = col + T;                         // <=256
    float* h0   = (float*)d_out;                   // N*256 scratch (overwritten at end)

    const int nb256  = (N + 255) / 256;            // 196
    const int nbT    = (T + 255) / 256;
    const int gm     = (N + TILE_M - 1) / TILE_M;  // 391

    // node = 0 (scatter may not cover all rows in general)
    hipMemsetAsync(fA, 0, (size_t)N * 256 * sizeof(float), stream);

    // feats: two halves, gelu+scatter into node
    gemm_fp32<1><<<dim3(gm, 1), 256, 0, stream>>>(img, w_img,  b_img,  fA, ci, N, 768, 128, 0);
    gemm_fp32<1><<<dim3(gm, 1), 256, 0, stream>>>(txt, w_text, b_text, fA, ci, N, 768, 128, 128);

    // CSR build (shared by both layers)
    init_cnt<<<nb256, 256, 0, stream>>>(cur, N);
    count_edges<<<(E + 255) / 256, 256, 0, stream>>>(edges, cur, E);
    scan1<<<nb256, 256, 0, stream>>>(cur, rs, bsum, N);
    scan2<<<1, 256, 0, stream>>>(bsum, nb256);
    scan3<<<nb256, 256, 0, stream>>>(rs, bsum, N, T);
    copy_cursor<<<nb256, 256, 0, stream>>>(rs, cur, N);
    fill_csr<<<nbT, 256, 0, stream>>>(edges, cur, col, E, N);

    // ---- layer 0 ----
    gemm_fp32<0><<<dim3(gm, 2), 256, 0, stream>>>(fA, W0, nullptr, h0, nullptr, N, 256, 256, 0);
    scores_kernel<<<(N + 3) / 4, 256, 0, stream>>>(h0, asrc0, adst0, sS, sD, N);
    attn_kernel<0><<<N, 256, 0, stream>>>(h0, sS, sD, rs, col, bias0, fB, N);

    // ---- layer 1 ----
    gemm_fp32<0><<<dim3(gm, 2), 256, 0, stream>>>(fB, W1, nullptr, fA, nullptr, N, 256, 256, 0);
    scores_kernel<<<(N + 3) / 4, 256, 0, stream>>>(fA, asrc1, adst1, sS, sD, N);
    attn_kernel<1><<<N, 256, 0, stream>>>(fA, sS, sD, rs, col, bias1, (float*)d_out, N);
}

// Round 3
// 839.975 us; speedup vs baseline: 1.3035x; 1.3035x over previous
//
#include <hip/hip_runtime.h>
#include <math.h>

// ---------------------------------------------------------------------------
// GraphConv (2-layer GAT) pipeline.
// GEMMs: split-bf16 MFMA (each fp32 = hi+lo bf16 interleaved along K, K'=2K)
//   -> fp32-class accuracy at bf16 matrix-core rate.
// R3 fix: packsplit uses round-to-nearest-even for BOTH halves (pair error
//   <= 2^-16 |f|, unbiased) instead of truncation (2^-14, biased) — R2
//   failed accuracy by 12% from exactly this.
// ---------------------------------------------------------------------------

typedef __attribute__((ext_vector_type(8))) short bf16x8;
typedef __attribute__((ext_vector_type(4))) float f32x4;

__device__ __forceinline__ float gelu_exact(float x) {
    return 0.5f * x * (1.0f + erff(x * 0.70710678118654752f));
}

// round-to-nearest-even bf16; returns the f32 bit pattern of the rounded value
__device__ __forceinline__ unsigned int rne_bf16_bits(float f) {
    unsigned int u = __float_as_uint(f);
    unsigned int r = u + 0x7FFFu + ((u >> 16) & 1u);
    return r & 0xFFFF0000u;
}

// fp32 -> packed (hi bf16 | lo bf16<<16), RNE split.
// hi = rne_bf16(f); resid = f - hi (exact, Sterbenz); lo = rne_bf16(resid).
__device__ __forceinline__ unsigned int packsplit(float f) {
    unsigned int hi_bits = rne_bf16_bits(f);
    float resid = f - __uint_as_float(hi_bits);
    unsigned int lo_bits = rne_bf16_bits(resid);
    return (hi_bits >> 16) | lo_bits;
}

// Pre-convert weight W[K][Bcols] fp32 -> Bt[col][2K] bf16 (hi,lo interleaved).
__global__ void conv_wt(const float* __restrict__ B, ushort* __restrict__ Bt,
                        int K, int Bcols)
{
    int t = blockIdx.x * 256 + threadIdx.x;
    int total = Bcols * (K >> 2);
    if (t >= total) return;
    int col = t % Bcols;
    int k4  = t / Bcols;          // group of 4 k values
    uint4 w;
    w.x = packsplit(B[(size_t)(4 * k4 + 0) * Bcols + col]);
    w.y = packsplit(B[(size_t)(4 * k4 + 1) * Bcols + col]);
    w.z = packsplit(B[(size_t)(4 * k4 + 2) * Bcols + col]);
    w.w = packsplit(B[(size_t)(4 * k4 + 3) * Bcols + col]);
    *(uint4*)&Bt[(size_t)col * 2 * K + 8 * k4] = w;
}

// ---------------------------------------------------------------------------
// Split-bf16 MFMA GEMM. C[M x Ncols] = A[M x K] @ B (via Bt bf16 [col][2K]).
// Tile 128x128, 256 threads = 4 waves (2x2), 16x16x32 bf16 MFMA.
// EPI=0: C[row*256 + colt+col] = acc
// EPI=1: C[ci[row]*256 + col_base + col] = gelu(acc + bias[col])   (colt==0)
// ---------------------------------------------------------------------------
template<int EPI>
__global__ __launch_bounds__(256)
void gemm_mfma(const float* __restrict__ A, const ushort* __restrict__ Bt,
               const float* __restrict__ bias, float* __restrict__ C,
               const int* __restrict__ ci, int M, int K, int col_base)
{
    __shared__ ushort As[128 * 64];   // [row][k'] k'=64 bf16 per K-step, XOR-swizzled
    __shared__ ushort Bs[128 * 64];   // [col][k'] same layout

    const int tid  = threadIdx.x;
    const int lane = tid & 63;
    const int w    = tid >> 6;
    const int wr   = w >> 1, wc = w & 1;      // wave -> 64x64 quadrant
    const int row0 = blockIdx.x * 128;
    const int colt = blockIdx.y * 128;
    const int K2   = 2 * K;

    f32x4 acc[4][4];
#pragma unroll
    for (int m = 0; m < 4; m++)
#pragma unroll
        for (int n = 0; n < 4; n++) acc[m][n] = (f32x4)0.f;

    for (int k0 = 0; k0 < K; k0 += 32) {
        // ---- stage A: 128 rows x 32 fp32 -> 64 bf16/row, convert + swizzle ----
#pragma unroll
        for (int p = 0; p < 4; p++) {
            int idx = tid + p * 256;
            int r   = idx >> 3;               // 0..127
            int c4  = (idx & 7) * 4;          // fp32 col 0..28
            int gr  = row0 + r;
            float4 v = make_float4(0.f, 0.f, 0.f, 0.f);
            if (gr < M) v = *(const float4*)&A[(size_t)gr * K + k0 + c4];
            uint4 wv;
            wv.x = packsplit(v.x); wv.y = packsplit(v.y);
            wv.z = packsplit(v.z); wv.w = packsplit(v.w);
            int elem = r * 64 + ((2 * c4) ^ ((r & 7) << 3));
            *(uint4*)&As[elem] = wv;
        }
        // ---- stage B: copy 128 cols x 64 bf16 from Bt (already converted) ----
#pragma unroll
        for (int p = 0; p < 4; p++) {
            int u   = tid + p * 256;
            int col = u & 127;
            int kg  = u >> 7;                 // 0..7, 8 bf16 each
            uint4 wv = *(const uint4*)&Bt[(size_t)(colt + col) * K2 + 2 * k0 + kg * 8];
            int elem = col * 64 + ((kg * 8) ^ ((col & 7) << 3));
            *(uint4*)&Bs[elem] = wv;
        }
        __syncthreads();

        // ---- fragments + MFMA ----
        bf16x8 af[4][2], bfr[4][2];
#pragma unroll
        for (int m = 0; m < 4; m++) {
            int row = wr * 64 + m * 16 + (lane & 15);
#pragma unroll
            for (int kb = 0; kb < 2; kb++) {
                int kp = kb * 32 + (lane >> 4) * 8;
                af[m][kb] = *(const bf16x8*)&As[row * 64 + (kp ^ ((row & 7) << 3))];
            }
        }
#pragma unroll
        for (int n = 0; n < 4; n++) {
            int col = wc * 64 + n * 16 + (lane & 15);
#pragma unroll
            for (int kb = 0; kb < 2; kb++) {
                int kp = kb * 32 + (lane >> 4) * 8;
                bfr[n][kb] = *(const bf16x8*)&Bs[col * 64 + (kp ^ ((col & 7) << 3))];
            }
        }
#pragma unroll
        for (int m = 0; m < 4; m++)
#pragma unroll
            for (int n = 0; n < 4; n++) {
                acc[m][n] = __builtin_amdgcn_mfma_f32_16x16x32_bf16(
                    af[m][0], bfr[n][0], acc[m][n], 0, 0, 0);
                acc[m][n] = __builtin_amdgcn_mfma_f32_16x16x32_bf16(
                    af[m][1], bfr[n][1], acc[m][n], 0, 0, 0);
            }
        __syncthreads();
    }

    // ---- epilogue: C/D layout col=lane&15, row=(lane>>4)*4+reg ----
#pragma unroll
    for (int m = 0; m < 4; m++) {
        int rbase = row0 + wr * 64 + m * 16 + ((lane >> 4) << 2);
#pragma unroll
        for (int n = 0; n < 4; n++) {
            int col = colt + wc * 64 + n * 16 + (lane & 15);
#pragma unroll
            for (int j = 0; j < 4; j++) {
                int grow = rbase + j;
                if (grow >= M) continue;
                float v = acc[m][n][j];
                if (EPI == 1) {
                    v = gelu_exact(v + bias[col]);
                    C[(size_t)ci[grow] * 256 + col_base + col] = v;
                } else {
                    C[(size_t)grow * 256 + col] = v;
                }
            }
        }
    }
}

// per-node attention scores: s_src[n] = h[n].asrc, s_dst[n] = h[n].adst
__global__ __launch_bounds__(256)
void scores_kernel(const float* __restrict__ h, const float* __restrict__ asrc,
                   const float* __restrict__ adst, float* __restrict__ s_src,
                   float* __restrict__ s_dst, int N)
{
    int wave = threadIdx.x >> 6;
    int lane = threadIdx.x & 63;
    int n = blockIdx.x * 4 + wave;
    if (n >= N) return;
    float4 hv = *(const float4*)&h[(size_t)n * 256 + lane * 4];
    float4 av = *(const float4*)&asrc[lane * 4];
    float4 dv = *(const float4*)&adst[lane * 4];
    float ps = hv.x * av.x + hv.y * av.y + hv.z * av.z + hv.w * av.w;
    float pd = hv.x * dv.x + hv.y * dv.y + hv.z * dv.z + hv.w * dv.w;
#pragma unroll
    for (int off = 32; off; off >>= 1) {
        ps += __shfl_xor(ps, off);
        pd += __shfl_xor(pd, off);
    }
    if (lane == 0) { s_src[n] = ps; s_dst[n] = pd; }
}

// ---- CSR build ----
__global__ void init_cnt(int* cnt, int N) {
    int i = blockIdx.x * 256 + threadIdx.x;
    if (i < N) cnt[i] = 1;   // self loop
}

__global__ void count_edges(const int* __restrict__ edges, int* cnt, int E) {
    int e = blockIdx.x * 256 + threadIdx.x;
    if (e < E) atomicAdd(&cnt[edges[2 * e + 1]], 1);
}

__global__ void scan1(const int* __restrict__ cnt, int* __restrict__ rs,
                      int* __restrict__ bsum, int N)
{
    __shared__ int sm[256];
    int tid = threadIdx.x;
    int i = blockIdx.x * 256 + tid;
    int v = (i < N) ? cnt[i] : 0;
    sm[tid] = v;
    __syncthreads();
    for (int off = 1; off < 256; off <<= 1) {
        int t = (tid >= off) ? sm[tid - off] : 0;
        __syncthreads();
        sm[tid] += t;
        __syncthreads();
    }
    if (i < N) rs[i] = sm[tid] - v;
    if (tid == 255) bsum[blockIdx.x] = sm[255];
}

__global__ void scan2(int* bsum, int nb) {
    __shared__ int sm[256];
    int tid = threadIdx.x;
    int v = (tid < nb) ? bsum[tid] : 0;
    sm[tid] = v;
    __syncthreads();
    for (int off = 1; off < 256; off <<= 1) {
        int t = (tid >= off) ? sm[tid - off] : 0;
        __syncthreads();
        sm[tid] += t;
        __syncthreads();
    }
    if (tid < nb) bsum[tid] = sm[tid] - v;
}

__global__ void scan3(int* __restrict__ rs, const int* __restrict__ bsum,
                      int N, int total)
{
    int i = blockIdx.x * 256 + threadIdx.x;
    if (i < N) rs[i] += bsum[i >> 8];
    if (i == 0) rs[N] = total;
}

__global__ void copy_cursor(const int* __restrict__ rs, int* __restrict__ cur, int N) {
    int i = blockIdx.x * 256 + threadIdx.x;
    if (i < N) cur[i] = rs[i];
}

__global__ void fill_csr(const int* __restrict__ edges, int* __restrict__ cur,
                         int* __restrict__ col, int E, int N)
{
    int i = blockIdx.x * 256 + threadIdx.x;
    if (i < E) {
        int s = edges[2 * i], d = edges[2 * i + 1];
        col[atomicAdd(&cur[d], 1)] = s;
    } else if (i < E + N) {
        int n = i - E;
        col[atomicAdd(&cur[n], 1)] = n;
    }
}

// per-dst-node attention aggregation. thread t owns output element t.
template<int EPI>
__global__ __launch_bounds__(256)
void attn_kernel(const float* __restrict__ h, const float* __restrict__ s_src,
                 const float* __restrict__ s_dst, const int* __restrict__ rs,
                 const int* __restrict__ col, const float* __restrict__ bias,
                 float* __restrict__ out, int N)
{
    int n = blockIdx.x;
    int t = threadIdx.x;
    float sd = s_dst[n];
    int beg = rs[n], end = rs[n + 1];
    float acc = 0.f, den = 0.f;
    for (int s = beg; s < end; ++s) {
        int src = col[s];
        float e = s_src[src] + sd;
        e = (e > 0.f) ? e : 0.2f * e;
        float wgt = expf(e);
        den += wgt;
        acc = fmaf(wgt, h[(size_t)src * 256 + t], acc);
    }
    float v = acc / den + bias[t];
    out[(size_t)n * 256 + t] = (EPI == 1) ? gelu_exact(v) : fmaxf(v, 0.f);
}

extern "C" void kernel_launch(void* const* d_in, const int* in_sizes, int n_in,
                              void* d_out, int out_size, void* d_ws, size_t ws_size,
                              hipStream_t stream)
{
    const float* img    = (const float*)d_in[0];
    const float* txt    = (const float*)d_in[1];
    const int*   ci     = (const int*)d_in[2];
    const int*   edges  = (const int*)d_in[3];
    const float* w_img  = (const float*)d_in[4];
    const float* b_img  = (const float*)d_in[5];
    const float* w_text = (const float*)d_in[6];
    const float* b_text = (const float*)d_in[7];
    const float* W0     = (const float*)d_in[8];
    const float* asrc0  = (const float*)d_in[9];
    const float* adst0  = (const float*)d_in[10];
    const float* bias0  = (const float*)d_in[11];
    const float* W1     = (const float*)d_in[12];
    const float* asrc1  = (const float*)d_in[13];
    const float* adst1  = (const float*)d_in[14];
    const float* bias1  = (const float*)d_in[15];

    const int N = in_sizes[2];
    const int E = in_sizes[3] / 2;
    const int T = E + N;

    // workspace layout
    float* fA   = (float*)d_ws;                    // node, later h1   N*256
    float* fB   = fA + (size_t)N * 256;            // out0             N*256
    float* sS   = fB + (size_t)N * 256;            // N
    float* sD   = sS + N;                          // N
    int*   rs   = (int*)(sD + N);                  // N+1
    int*   cur  = rs + (N + 1);                    // N
    int*   col  = cur + N;                         // E+N
    int*   bsum = col + T;                         // <=256
    // bf16 weight buffers, 64B aligned
    uintptr_t bt0 = ((uintptr_t)(bsum + 256) + 63) & ~(uintptr_t)63;
    ushort* BtImg = (ushort*)bt0;                  // 128 x 1536
    ushort* BtTxt = BtImg + 128 * 1536;            // 128 x 1536
    ushort* BtW0  = BtTxt + 128 * 1536;            // 256 x 512
    ushort* BtW1  = BtW0  + 256 * 512;             // 256 x 512
    float* h0   = (float*)d_out;                   // N*256 scratch

    const int nb256 = (N + 255) / 256;
    const int nbT   = (T + 255) / 256;
    const int gm    = (N + 127) / 128;             // 391

    // weight pre-conversion (tiny)
    conv_wt<<<(128 * 192 + 255) / 256, 256, 0, stream>>>(w_img,  BtImg, 768, 128);
    conv_wt<<<(128 * 192 + 255) / 256, 256, 0, stream>>>(w_text, BtTxt, 768, 128);
    conv_wt<<<(256 * 64  + 255) / 256, 256, 0, stream>>>(W0,     BtW0,  256, 256);
    conv_wt<<<(256 * 64  + 255) / 256, 256, 0, stream>>>(W1,     BtW1,  256, 256);

    hipMemsetAsync(fA, 0, (size_t)N * 256 * sizeof(float), stream);

    // upscale GEMMs: gelu(bias+acc) scattered into node
    gemm_mfma<1><<<dim3(gm, 1), 256, 0, stream>>>(img, BtImg, b_img,  fA, ci, N, 768, 0);
    gemm_mfma<1><<<dim3(gm, 1), 256, 0, stream>>>(txt, BtTxt, b_text, fA, ci, N, 768, 128);

    // CSR build (shared by both layers)
    init_cnt<<<nb256, 256, 0, stream>>>(cur, N);
    count_edges<<<(E + 255) / 256, 256, 0, stream>>>(edges, cur, E);
    scan1<<<nb256, 256, 0, stream>>>(cur, rs, bsum, N);
    scan2<<<1, 256, 0, stream>>>(bsum, nb256);
    scan3<<<nb256, 256, 0, stream>>>(rs, bsum, N, T);
    copy_cursor<<<nb256, 256, 0, stream>>>(rs, cur, N);
    fill_csr<<<nbT, 256, 0, stream>>>(edges, cur, col, E, N);

    // ---- layer 0 ----
    gemm_mfma<0><<<dim3(gm, 2), 256, 0, stream>>>(fA, BtW0, nullptr, h0, nullptr, N, 256, 0);
    scores_kernel<<<(N + 3) / 4, 256, 0, stream>>>(h0, asrc0, adst0, sS, sD, N);
    attn_kernel<0><<<N, 256, 0, stream>>>(h0, sS, sD, rs, col, bias0, fB, N);

    // ---- layer 1 ----
    gemm_mfma<0><<<dim3(gm, 2), 256, 0, stream>>>(fB, BtW1, nullptr, fA, nullptr, N, 256, 0);
    scores_kernel<<<(N + 3) / 4, 256, 0, stream>>>(fA, asrc1, adst1, sS, sD, N);
    attn_kernel<1><<<N, 256, 0, stream>>>(fA, sS, sD, rs, col, bias1, (float*)d_out, N);
}

// Round 4
// 703.648 us; speedup vs baseline: 1.5560x; 1.1937x over previous
//
#include <hip/hip_runtime.h>
#include <math.h>

// ---------------------------------------------------------------------------
// GraphConv (2-layer GAT) pipeline.
// GEMMs: split-bf16 MFMA (fp32 = hi+lo bf16 RNE pair along K, K'=2K).
// R4: restructured attn_kernel — per-block 2-phase (parallel weight pass into
//   LDS, then 4-wave float4 gather with 8 rows in flight) to break the
//   ~1000cy serial col->s_src->exp->h chain that made R3's attn latency-bound.
// ---------------------------------------------------------------------------

typedef __attribute__((ext_vector_type(8))) short bf16x8;
typedef __attribute__((ext_vector_type(4))) float f32x4;

__device__ __forceinline__ float gelu_exact(float x) {
    return 0.5f * x * (1.0f + erff(x * 0.70710678118654752f));
}

// round-to-nearest-even bf16; returns the f32 bit pattern of the rounded value
__device__ __forceinline__ unsigned int rne_bf16_bits(float f) {
    unsigned int u = __float_as_uint(f);
    unsigned int r = u + 0x7FFFu + ((u >> 16) & 1u);
    return r & 0xFFFF0000u;
}

// fp32 -> packed (hi bf16 | lo bf16<<16), RNE split.
__device__ __forceinline__ unsigned int packsplit(float f) {
    unsigned int hi_bits = rne_bf16_bits(f);
    float resid = f - __uint_as_float(hi_bits);
    unsigned int lo_bits = rne_bf16_bits(resid);
    return (hi_bits >> 16) | lo_bits;
}

// Pre-convert weight W[K][Bcols] fp32 -> Bt[col][2K] bf16 (hi,lo interleaved).
__global__ void conv_wt(const float* __restrict__ B, ushort* __restrict__ Bt,
                        int K, int Bcols)
{
    int t = blockIdx.x * 256 + threadIdx.x;
    int total = Bcols * (K >> 2);
    if (t >= total) return;
    int col = t % Bcols;
    int k4  = t / Bcols;
    uint4 w;
    w.x = packsplit(B[(size_t)(4 * k4 + 0) * Bcols + col]);
    w.y = packsplit(B[(size_t)(4 * k4 + 1) * Bcols + col]);
    w.z = packsplit(B[(size_t)(4 * k4 + 2) * Bcols + col]);
    w.w = packsplit(B[(size_t)(4 * k4 + 3) * Bcols + col]);
    *(uint4*)&Bt[(size_t)col * 2 * K + 8 * k4] = w;
}

// ---------------------------------------------------------------------------
// Split-bf16 MFMA GEMM. Tile 128x128, 4 waves (2x2), 16x16x32 bf16 MFMA.
// ---------------------------------------------------------------------------
template<int EPI>
__global__ __launch_bounds__(256)
void gemm_mfma(const float* __restrict__ A, const ushort* __restrict__ Bt,
               const float* __restrict__ bias, float* __restrict__ C,
               const int* __restrict__ ci, int M, int K, int col_base)
{
    __shared__ ushort As[128 * 64];
    __shared__ ushort Bs[128 * 64];

    const int tid  = threadIdx.x;
    const int lane = tid & 63;
    const int w    = tid >> 6;
    const int wr   = w >> 1, wc = w & 1;
    const int row0 = blockIdx.x * 128;
    const int colt = blockIdx.y * 128;
    const int K2   = 2 * K;

    f32x4 acc[4][4];
#pragma unroll
    for (int m = 0; m < 4; m++)
#pragma unroll
        for (int n = 0; n < 4; n++) acc[m][n] = (f32x4)0.f;

    for (int k0 = 0; k0 < K; k0 += 32) {
#pragma unroll
        for (int p = 0; p < 4; p++) {
            int idx = tid + p * 256;
            int r   = idx >> 3;
            int c4  = (idx & 7) * 4;
            int gr  = row0 + r;
            float4 v = make_float4(0.f, 0.f, 0.f, 0.f);
            if (gr < M) v = *(const float4*)&A[(size_t)gr * K + k0 + c4];
            uint4 wv;
            wv.x = packsplit(v.x); wv.y = packsplit(v.y);
            wv.z = packsplit(v.z); wv.w = packsplit(v.w);
            int elem = r * 64 + ((2 * c4) ^ ((r & 7) << 3));
            *(uint4*)&As[elem] = wv;
        }
#pragma unroll
        for (int p = 0; p < 4; p++) {
            int u   = tid + p * 256;
            int col = u & 127;
            int kg  = u >> 7;
            uint4 wv = *(const uint4*)&Bt[(size_t)(colt + col) * K2 + 2 * k0 + kg * 8];
            int elem = col * 64 + ((kg * 8) ^ ((col & 7) << 3));
            *(uint4*)&Bs[elem] = wv;
        }
        __syncthreads();

        bf16x8 af[4][2], bfr[4][2];
#pragma unroll
        for (int m = 0; m < 4; m++) {
            int row = wr * 64 + m * 16 + (lane & 15);
#pragma unroll
            for (int kb = 0; kb < 2; kb++) {
                int kp = kb * 32 + (lane >> 4) * 8;
                af[m][kb] = *(const bf16x8*)&As[row * 64 + (kp ^ ((row & 7) << 3))];
            }
        }
#pragma unroll
        for (int n = 0; n < 4; n++) {
            int col = wc * 64 + n * 16 + (lane & 15);
#pragma unroll
            for (int kb = 0; kb < 2; kb++) {
                int kp = kb * 32 + (lane >> 4) * 8;
                bfr[n][kb] = *(const bf16x8*)&Bs[col * 64 + (kp ^ ((col & 7) << 3))];
            }
        }
#pragma unroll
        for (int m = 0; m < 4; m++)
#pragma unroll
            for (int n = 0; n < 4; n++) {
                acc[m][n] = __builtin_amdgcn_mfma_f32_16x16x32_bf16(
                    af[m][0], bfr[n][0], acc[m][n], 0, 0, 0);
                acc[m][n] = __builtin_amdgcn_mfma_f32_16x16x32_bf16(
                    af[m][1], bfr[n][1], acc[m][n], 0, 0, 0);
            }
        __syncthreads();
    }

#pragma unroll
    for (int m = 0; m < 4; m++) {
        int rbase = row0 + wr * 64 + m * 16 + ((lane >> 4) << 2);
#pragma unroll
        for (int n = 0; n < 4; n++) {
            int col = colt + wc * 64 + n * 16 + (lane & 15);
#pragma unroll
            for (int j = 0; j < 4; j++) {
                int grow = rbase + j;
                if (grow >= M) continue;
                float v = acc[m][n][j];
                if (EPI == 1) {
                    v = gelu_exact(v + bias[col]);
                    C[(size_t)ci[grow] * 256 + col_base + col] = v;
                } else {
                    C[(size_t)grow * 256 + col] = v;
                }
            }
        }
    }
}

// per-node attention scores
__global__ __launch_bounds__(256)
void scores_kernel(const float* __restrict__ h, const float* __restrict__ asrc,
                   const float* __restrict__ adst, float* __restrict__ s_src,
                   float* __restrict__ s_dst, int N)
{
    int wave = threadIdx.x >> 6;
    int lane = threadIdx.x & 63;
    int n = blockIdx.x * 4 + wave;
    if (n >= N) return;
    float4 hv = *(const float4*)&h[(size_t)n * 256 + lane * 4];
    float4 av = *(const float4*)&asrc[lane * 4];
    float4 dv = *(const float4*)&adst[lane * 4];
    float ps = hv.x * av.x + hv.y * av.y + hv.z * av.z + hv.w * av.w;
    float pd = hv.x * dv.x + hv.y * dv.y + hv.z * dv.z + hv.w * dv.w;
#pragma unroll
    for (int off = 32; off; off >>= 1) {
        ps += __shfl_xor(ps, off);
        pd += __shfl_xor(pd, off);
    }
    if (lane == 0) { s_src[n] = ps; s_dst[n] = pd; }
}

// ---- CSR build ----
__global__ void init_cnt(int* cnt, int N) {
    int i = blockIdx.x * 256 + threadIdx.x;
    if (i < N) cnt[i] = 1;
}

__global__ void count_edges(const int* __restrict__ edges, int* cnt, int E) {
    int e = blockIdx.x * 256 + threadIdx.x;
    if (e < E) atomicAdd(&cnt[edges[2 * e + 1]], 1);
}

__global__ void scan1(const int* __restrict__ cnt, int* __restrict__ rs,
                      int* __restrict__ bsum, int N)
{
    __shared__ int sm[256];
    int tid = threadIdx.x;
    int i = blockIdx.x * 256 + tid;
    int v = (i < N) ? cnt[i] : 0;
    sm[tid] = v;
    __syncthreads();
    for (int off = 1; off < 256; off <<= 1) {
        int t = (tid >= off) ? sm[tid - off] : 0;
        __syncthreads();
        sm[tid] += t;
        __syncthreads();
    }
    if (i < N) rs[i] = sm[tid] - v;
    if (tid == 255) bsum[blockIdx.x] = sm[255];
}

__global__ void scan2(int* bsum, int nb) {
    __shared__ int sm[256];
    int tid = threadIdx.x;
    int v = (tid < nb) ? bsum[tid] : 0;
    sm[tid] = v;
    __syncthreads();
    for (int off = 1; off < 256; off <<= 1) {
        int t = (tid >= off) ? sm[tid - off] : 0;
        __syncthreads();
        sm[tid] += t;
        __syncthreads();
    }
    if (tid < nb) bsum[tid] = sm[tid] - v;
}

__global__ void scan3(int* __restrict__ rs, const int* __restrict__ bsum,
                      int N, int total)
{
    int i = blockIdx.x * 256 + threadIdx.x;
    if (i < N) rs[i] += bsum[i >> 8];
    if (i == 0) rs[N] = total;
}

__global__ void copy_cursor(const int* __restrict__ rs, int* __restrict__ cur, int N) {
    int i = blockIdx.x * 256 + threadIdx.x;
    if (i < N) cur[i] = rs[i];
}

__global__ void fill_csr(const int* __restrict__ edges, int* __restrict__ cur,
                         int* __restrict__ col, int E, int N)
{
    int i = blockIdx.x * 256 + threadIdx.x;
    if (i < E) {
        int s = edges[2 * i], d = edges[2 * i + 1];
        col[atomicAdd(&cur[d], 1)] = s;
    } else if (i < E + N) {
        int n = i - E;
        col[atomicAdd(&cur[n], 1)] = n;
    }
}

// ---------------------------------------------------------------------------
// attn: block per dst node, 2-phase.
//  phase 1: up-to-256 edge weights computed in parallel (one exp per edge),
//           (src, w) cached in LDS.
//  phase 2: 4 waves, each covers all 256 cols via float4/lane, edges strided
//           by 4 and unrolled x2 -> 8 independent h-row loads in flight.
//  final:   cross-wave LDS reduce, divide by den once, bias + activation.
// ---------------------------------------------------------------------------
template<int EPI>
__global__ __launch_bounds__(256)
void attn_kernel(const float* __restrict__ h, const float* __restrict__ s_src,
                 const float* __restrict__ s_dst, const int* __restrict__ rs,
                 const int* __restrict__ colv, const float* __restrict__ bias,
                 float* __restrict__ out, int N)
{
    __shared__ float wlds[256];
    __shared__ int   slds[256];
    __shared__ float red[4][256];
    __shared__ float dred[4];

    const int n    = blockIdx.x;
    const int tid  = threadIdx.x;
    const int w    = tid >> 6;
    const int lane = tid & 63;

    const float sd = s_dst[n];
    const int beg = rs[n], end = rs[n + 1];

    float4 acc = make_float4(0.f, 0.f, 0.f, 0.f);
    float den = 0.f;

    for (int c0 = beg; c0 < end; c0 += 256) {
        const int cnt = min(256, end - c0);
        __syncthreads();                       // protect LDS reuse across chunks
        if (tid < cnt) {
            int src = colv[c0 + tid];
            float e = s_src[src] + sd;
            e = (e > 0.f) ? e : 0.2f * e;
            wlds[tid] = __expf(e);
            slds[tid] = src;
        }
        __syncthreads();

        int i = w;
        for (; i + 4 < cnt; i += 8) {          // 2 edges per wave per iter
            int   s0 = slds[i],     s1 = slds[i + 4];
            float w0 = wlds[i],     w1 = wlds[i + 4];
            float4 h0 = *(const float4*)&h[(size_t)s0 * 256 + lane * 4];
            float4 h1 = *(const float4*)&h[(size_t)s1 * 256 + lane * 4];
            acc.x = fmaf(w0, h0.x, acc.x); acc.y = fmaf(w0, h0.y, acc.y);
            acc.z = fmaf(w0, h0.z, acc.z); acc.w = fmaf(w0, h0.w, acc.w);
            acc.x = fmaf(w1, h1.x, acc.x); acc.y = fmaf(w1, h1.y, acc.y);
            acc.z = fmaf(w1, h1.z, acc.z); acc.w = fmaf(w1, h1.w, acc.w);
            den += w0 + w1;
        }
        if (i < cnt) {                         // at most one tail edge per wave
            int   s0 = slds[i];
            float w0 = wlds[i];
            float4 h0 = *(const float4*)&h[(size_t)s0 * 256 + lane * 4];
            acc.x = fmaf(w0, h0.x, acc.x); acc.y = fmaf(w0, h0.y, acc.y);
            acc.z = fmaf(w0, h0.z, acc.z); acc.w = fmaf(w0, h0.w, acc.w);
            den += w0;
        }
    }

    *(float4*)&red[w][lane * 4] = acc;
    if (lane == 0) dred[w] = den;
    __syncthreads();

    float v  = red[0][tid] + red[1][tid] + red[2][tid] + red[3][tid];
    float dn = dred[0] + dred[1] + dred[2] + dred[3];
    v = v / dn + bias[tid];
    out[(size_t)n * 256 + tid] = (EPI == 1) ? gelu_exact(v) : fmaxf(v, 0.f);
}

extern "C" void kernel_launch(void* const* d_in, const int* in_sizes, int n_in,
                              void* d_out, int out_size, void* d_ws, size_t ws_size,
                              hipStream_t stream)
{
    const float* img    = (const float*)d_in[0];
    const float* txt    = (const float*)d_in[1];
    const int*   ci     = (const int*)d_in[2];
    const int*   edges  = (const int*)d_in[3];
    const float* w_img  = (const float*)d_in[4];
    const float* b_img  = (const float*)d_in[5];
    const float* w_text = (const float*)d_in[6];
    const float* b_text = (const float*)d_in[7];
    const float* W0     = (const float*)d_in[8];
    const float* asrc0  = (const float*)d_in[9];
    const float* adst0  = (const float*)d_in[10];
    const float* bias0  = (const float*)d_in[11];
    const float* W1     = (const float*)d_in[12];
    const float* asrc1  = (const float*)d_in[13];
    const float* adst1  = (const float*)d_in[14];
    const float* bias1  = (const float*)d_in[15];

    const int N = in_sizes[2];
    const int E = in_sizes[3] / 2;
    const int T = E + N;

    float* fA   = (float*)d_ws;                    // node, later h1   N*256
    float* fB   = fA + (size_t)N * 256;            // out0             N*256
    float* sS   = fB + (size_t)N * 256;            // N
    float* sD   = sS + N;                          // N
    int*   rs   = (int*)(sD + N);                  // N+1
    int*   cur  = rs + (N + 1);                    // N
    int*   col  = cur + N;                         // E+N
    int*   bsum = col + T;                         // <=256
    uintptr_t bt0 = ((uintptr_t)(bsum + 256) + 63) & ~(uintptr_t)63;
    ushort* BtImg = (ushort*)bt0;                  // 128 x 1536
    ushort* BtTxt = BtImg + 128 * 1536;            // 128 x 1536
    ushort* BtW0  = BtTxt + 128 * 1536;            // 256 x 512
    ushort* BtW1  = BtW0  + 256 * 512;             // 256 x 512
    float* h0   = (float*)d_out;                   // N*256 scratch

    const int nb256 = (N + 255) / 256;
    const int nbT   = (T + 255) / 256;
    const int gm    = (N + 127) / 128;

    conv_wt<<<(128 * 192 + 255) / 256, 256, 0, stream>>>(w_img,  BtImg, 768, 128);
    conv_wt<<<(128 * 192 + 255) / 256, 256, 0, stream>>>(w_text, BtTxt, 768, 128);
    conv_wt<<<(256 * 64  + 255) / 256, 256, 0, stream>>>(W0,     BtW0,  256, 256);
    conv_wt<<<(256 * 64  + 255) / 256, 256, 0, stream>>>(W1,     BtW1,  256, 256);

    hipMemsetAsync(fA, 0, (size_t)N * 256 * sizeof(float), stream);

    gemm_mfma<1><<<dim3(gm, 1), 256, 0, stream>>>(img, BtImg, b_img,  fA, ci, N, 768, 0);
    gemm_mfma<1><<<dim3(gm, 1), 256, 0, stream>>>(txt, BtTxt, b_text, fA, ci, N, 768, 128);

    init_cnt<<<nb256, 256, 0, stream>>>(cur, N);
    count_edges<<<(E + 255) / 256, 256, 0, stream>>>(edges, cur, E);
    scan1<<<nb256, 256, 0, stream>>>(cur, rs, bsum, N);
    scan2<<<1, 256, 0, stream>>>(bsum, nb256);
    scan3<<<nb256, 256, 0, stream>>>(rs, bsum, N, T);
    copy_cursor<<<nb256, 256, 0, stream>>>(rs, cur, N);
    fill_csr<<<nbT, 256, 0, stream>>>(edges, cur, col, E, N);

    // ---- layer 0 ----
    gemm_mfma<0><<<dim3(gm, 2), 256, 0, stream>>>(fA, BtW0, nullptr, h0, nullptr, N, 256, 0);
    scores_kernel<<<(N + 3) / 4, 256, 0, stream>>>(h0, asrc0, adst0, sS, sD, N);
    attn_kernel<0><<<N, 256, 0, stream>>>(h0, sS, sD, rs, col, bias0, fB, N);

    // ---- layer 1 ----
    gemm_mfma<0><<<dim3(gm, 2), 256, 0, stream>>>(fB, BtW1, nullptr, fA, nullptr, N, 256, 0);
    scores_kernel<<<(N + 3) / 4, 256, 0, stream>>>(fA, asrc1, adst1, sS, sD, N);
    attn_kernel<1><<<N, 256, 0, stream>>>(fA, sS, sD, rs, col, bias1, (float*)d_out, N);
}

// Round 5
// 663.196 us; speedup vs baseline: 1.6509x; 1.0610x over previous
//
#include <hip/hip_runtime.h>
#include <math.h>

// ---------------------------------------------------------------------------
// GraphConv (2-layer GAT) pipeline.
// GEMMs: split-bf16 MFMA (fp32 = hi+lo bf16 RNE pair along K, K'=2K).
// R5: GEMM occupancy fix — R4's 128x128 tile gave 391 blocks = 1.5/CU
//   (Occupancy 16%, MfmaUtil 5.7%, VALUBusy 12%: nothing busy = latency
//   bound). Now TILE_M=64 (782 row tiles) and both upscale GEMMs merged
//   into one grid-(782,2) launch -> ~6 blocks/CU.
// ---------------------------------------------------------------------------

typedef __attribute__((ext_vector_type(8))) short bf16x8;
typedef __attribute__((ext_vector_type(4))) float f32x4;

__device__ __forceinline__ float gelu_exact(float x) {
    return 0.5f * x * (1.0f + erff(x * 0.70710678118654752f));
}

// round-to-nearest-even bf16; returns the f32 bit pattern of the rounded value
__device__ __forceinline__ unsigned int rne_bf16_bits(float f) {
    unsigned int u = __float_as_uint(f);
    unsigned int r = u + 0x7FFFu + ((u >> 16) & 1u);
    return r & 0xFFFF0000u;
}

// fp32 -> packed (hi bf16 | lo bf16<<16), RNE split.
__device__ __forceinline__ unsigned int packsplit(float f) {
    unsigned int hi_bits = rne_bf16_bits(f);
    float resid = f - __uint_as_float(hi_bits);
    unsigned int lo_bits = rne_bf16_bits(resid);
    return (hi_bits >> 16) | lo_bits;
}

// Pre-convert weight W[K][Bcols] fp32 -> Bt[col][2K] bf16 (hi,lo interleaved).
__global__ void conv_wt(const float* __restrict__ B, ushort* __restrict__ Bt,
                        int K, int Bcols)
{
    int t = blockIdx.x * 256 + threadIdx.x;
    int total = Bcols * (K >> 2);
    if (t >= total) return;
    int col = t % Bcols;
    int k4  = t / Bcols;
    uint4 w;
    w.x = packsplit(B[(size_t)(4 * k4 + 0) * Bcols + col]);
    w.y = packsplit(B[(size_t)(4 * k4 + 1) * Bcols + col]);
    w.z = packsplit(B[(size_t)(4 * k4 + 2) * Bcols + col]);
    w.w = packsplit(B[(size_t)(4 * k4 + 3) * Bcols + col]);
    *(uint4*)&Bt[(size_t)col * 2 * K + 8 * k4] = w;
}

// ---------------------------------------------------------------------------
// Split-bf16 MFMA GEMM, tile 64x128, 4 waves (2x2 of 32x64), 16x16x32 MFMA.
// MODE=0 (layer): A=A0,Bt=B0, colt=blockIdx.y*128, C[row*256+colt+col]=acc.
// MODE=1 (upscale): blockIdx.y selects {A0,B0,bias0,cb0}/{A1,...}, colt=0,
//                   C[ci[row]*256 + cb + col] = gelu(acc + bias[col]).
// ---------------------------------------------------------------------------
template<int MODE>
__global__ __launch_bounds__(256)
void gemm64(const float* __restrict__ A0, const float* __restrict__ A1,
            const ushort* __restrict__ B0, const ushort* __restrict__ B1,
            const float* __restrict__ bias0, const float* __restrict__ bias1,
            float* __restrict__ C, const int* __restrict__ ci,
            int M, int K, int cb0, int cb1)
{
    __shared__ ushort As[64 * 64];    // [row][k'] XOR-swizzled
    __shared__ ushort Bs[128 * 64];   // [col][k'] XOR-swizzled

    const int tid  = threadIdx.x;
    const int lane = tid & 63;
    const int w    = tid >> 6;
    const int wr   = w >> 1, wc = w & 1;      // wave -> 32x64 quadrant
    const int row0 = blockIdx.x * 64;

    const float* A; const ushort* Bt; const float* bias; int col_base, colt;
    if (MODE == 1) {
        int sel = blockIdx.y;
        A = sel ? A1 : A0; Bt = sel ? B1 : B0;
        bias = sel ? bias1 : bias0; col_base = sel ? cb1 : cb0;
        colt = 0;
    } else {
        A = A0; Bt = B0; bias = nullptr; col_base = 0;
        colt = blockIdx.y * 128;
    }
    const int K2 = 2 * K;

    f32x4 acc[2][4];
#pragma unroll
    for (int m = 0; m < 2; m++)
#pragma unroll
        for (int n = 0; n < 4; n++) acc[m][n] = (f32x4)0.f;

    for (int k0 = 0; k0 < K; k0 += 32) {
        // ---- stage A: 64 rows x 32 fp32 -> convert + swizzle (2 f4/thread) ----
#pragma unroll
        for (int p = 0; p < 2; p++) {
            int idx = tid + p * 256;
            int r   = idx >> 3;               // 0..63
            int c4  = (idx & 7) * 4;
            int gr  = row0 + r;
            float4 v = make_float4(0.f, 0.f, 0.f, 0.f);
            if (gr < M) v = *(const float4*)&A[(size_t)gr * K + k0 + c4];
            uint4 wv;
            wv.x = packsplit(v.x); wv.y = packsplit(v.y);
            wv.z = packsplit(v.z); wv.w = packsplit(v.w);
            int elem = r * 64 + ((2 * c4) ^ ((r & 7) << 3));
            *(uint4*)&As[elem] = wv;
        }
        // ---- stage B: 128 cols x 64 bf16 from Bt (4 uint4/thread) ----
#pragma unroll
        for (int p = 0; p < 4; p++) {
            int u   = tid + p * 256;
            int col = u & 127;
            int kg  = u >> 7;
            uint4 wv = *(const uint4*)&Bt[(size_t)(colt + col) * K2 + 2 * k0 + kg * 8];
            int elem = col * 64 + ((kg * 8) ^ ((col & 7) << 3));
            *(uint4*)&Bs[elem] = wv;
        }
        __syncthreads();

        bf16x8 af[2][2], bfr[4][2];
#pragma unroll
        for (int m = 0; m < 2; m++) {
            int row = wr * 32 + m * 16 + (lane & 15);
#pragma unroll
            for (int kb = 0; kb < 2; kb++) {
                int kp = kb * 32 + (lane >> 4) * 8;
                af[m][kb] = *(const bf16x8*)&As[row * 64 + (kp ^ ((row & 7) << 3))];
            }
        }
#pragma unroll
        for (int n = 0; n < 4; n++) {
            int col = wc * 64 + n * 16 + (lane & 15);
#pragma unroll
            for (int kb = 0; kb < 2; kb++) {
                int kp = kb * 32 + (lane >> 4) * 8;
                bfr[n][kb] = *(const bf16x8*)&Bs[col * 64 + (kp ^ ((col & 7) << 3))];
            }
        }
#pragma unroll
        for (int m = 0; m < 2; m++)
#pragma unroll
            for (int n = 0; n < 4; n++) {
                acc[m][n] = __builtin_amdgcn_mfma_f32_16x16x32_bf16(
                    af[m][0], bfr[n][0], acc[m][n], 0, 0, 0);
                acc[m][n] = __builtin_amdgcn_mfma_f32_16x16x32_bf16(
                    af[m][1], bfr[n][1], acc[m][n], 0, 0, 0);
            }
        __syncthreads();
    }

    // ---- epilogue: C/D layout col=lane&15, row=(lane>>4)*4+reg ----
#pragma unroll
    for (int m = 0; m < 2; m++) {
        int rbase = row0 + wr * 32 + m * 16 + ((lane >> 4) << 2);
#pragma unroll
        for (int n = 0; n < 4; n++) {
            int col = wc * 64 + n * 16 + (lane & 15);
#pragma unroll
            for (int j = 0; j < 4; j++) {
                int grow = rbase + j;
                if (grow >= M) continue;
                float v = acc[m][n][j];
                if (MODE == 1) {
                    v = gelu_exact(v + bias[col]);
                    C[(size_t)ci[grow] * 256 + col_base + col] = v;
                } else {
                    C[(size_t)grow * 256 + colt + col] = v;
                }
            }
        }
    }
}

// per-node attention scores
__global__ __launch_bounds__(256)
void scores_kernel(const float* __restrict__ h, const float* __restrict__ asrc,
                   const float* __restrict__ adst, float* __restrict__ s_src,
                   float* __restrict__ s_dst, int N)
{
    int wave = threadIdx.x >> 6;
    int lane = threadIdx.x & 63;
    int n = blockIdx.x * 4 + wave;
    if (n >= N) return;
    float4 hv = *(const float4*)&h[(size_t)n * 256 + lane * 4];
    float4 av = *(const float4*)&asrc[lane * 4];
    float4 dv = *(const float4*)&adst[lane * 4];
    float ps = hv.x * av.x + hv.y * av.y + hv.z * av.z + hv.w * av.w;
    float pd = hv.x * dv.x + hv.y * dv.y + hv.z * dv.z + hv.w * dv.w;
#pragma unroll
    for (int off = 32; off; off >>= 1) {
        ps += __shfl_xor(ps, off);
        pd += __shfl_xor(pd, off);
    }
    if (lane == 0) { s_src[n] = ps; s_dst[n] = pd; }
}

// ---- CSR build ----
__global__ void init_cnt(int* cnt, int N) {
    int i = blockIdx.x * 256 + threadIdx.x;
    if (i < N) cnt[i] = 1;
}

__global__ void count_edges(const int* __restrict__ edges, int* cnt, int E) {
    int e = blockIdx.x * 256 + threadIdx.x;
    if (e < E) atomicAdd(&cnt[edges[2 * e + 1]], 1);
}

__global__ void scan1(const int* __restrict__ cnt, int* __restrict__ rs,
                      int* __restrict__ bsum, int N)
{
    __shared__ int sm[256];
    int tid = threadIdx.x;
    int i = blockIdx.x * 256 + tid;
    int v = (i < N) ? cnt[i] : 0;
    sm[tid] = v;
    __syncthreads();
    for (int off = 1; off < 256; off <<= 1) {
        int t = (tid >= off) ? sm[tid - off] : 0;
        __syncthreads();
        sm[tid] += t;
        __syncthreads();
    }
    if (i < N) rs[i] = sm[tid] - v;
    if (tid == 255) bsum[blockIdx.x] = sm[255];
}

__global__ void scan2(int* bsum, int nb) {
    __shared__ int sm[256];
    int tid = threadIdx.x;
    int v = (tid < nb) ? bsum[tid] : 0;
    sm[tid] = v;
    __syncthreads();
    for (int off = 1; off < 256; off <<= 1) {
        int t = (tid >= off) ? sm[tid - off] : 0;
        __syncthreads();
        sm[tid] += t;
        __syncthreads();
    }
    if (tid < nb) bsum[tid] = sm[tid] - v;
}

__global__ void scan3(int* __restrict__ rs, const int* __restrict__ bsum,
                      int N, int total)
{
    int i = blockIdx.x * 256 + threadIdx.x;
    if (i < N) rs[i] += bsum[i >> 8];
    if (i == 0) rs[N] = total;
}

__global__ void copy_cursor(const int* __restrict__ rs, int* __restrict__ cur, int N) {
    int i = blockIdx.x * 256 + threadIdx.x;
    if (i < N) cur[i] = rs[i];
}

__global__ void fill_csr(const int* __restrict__ edges, int* __restrict__ cur,
                         int* __restrict__ col, int E, int N)
{
    int i = blockIdx.x * 256 + threadIdx.x;
    if (i < E) {
        int s = edges[2 * i], d = edges[2 * i + 1];
        col[atomicAdd(&cur[d], 1)] = s;
    } else if (i < E + N) {
        int n = i - E;
        col[atomicAdd(&cur[n], 1)] = n;
    }
}

// ---------------------------------------------------------------------------
// attn: block per dst node, 2-phase (parallel weights into LDS, then 4-wave
// float4 gather with 8 rows in flight), cross-wave reduce.
// ---------------------------------------------------------------------------
template<int EPI>
__global__ __launch_bounds__(256)
void attn_kernel(const float* __restrict__ h, const float* __restrict__ s_src,
                 const float* __restrict__ s_dst, const int* __restrict__ rs,
                 const int* __restrict__ colv, const float* __restrict__ bias,
                 float* __restrict__ out, int N)
{
    __shared__ float wlds[256];
    __shared__ int   slds[256];
    __shared__ float red[4][256];
    __shared__ float dred[4];

    const int n    = blockIdx.x;
    const int tid  = threadIdx.x;
    const int w    = tid >> 6;
    const int lane = tid & 63;

    const float sd = s_dst[n];
    const int beg = rs[n], end = rs[n + 1];

    float4 acc = make_float4(0.f, 0.f, 0.f, 0.f);
    float den = 0.f;

    for (int c0 = beg; c0 < end; c0 += 256) {
        const int cnt = min(256, end - c0);
        __syncthreads();
        if (tid < cnt) {
            int src = colv[c0 + tid];
            float e = s_src[src] + sd;
            e = (e > 0.f) ? e : 0.2f * e;
            wlds[tid] = __expf(e);
            slds[tid] = src;
        }
        __syncthreads();

        int i = w;
        for (; i + 4 < cnt; i += 8) {
            int   s0 = slds[i],     s1 = slds[i + 4];
            float w0 = wlds[i],     w1 = wlds[i + 4];
            float4 h0 = *(const float4*)&h[(size_t)s0 * 256 + lane * 4];
            float4 h1 = *(const float4*)&h[(size_t)s1 * 256 + lane * 4];
            acc.x = fmaf(w0, h0.x, acc.x); acc.y = fmaf(w0, h0.y, acc.y);
            acc.z = fmaf(w0, h0.z, acc.z); acc.w = fmaf(w0, h0.w, acc.w);
            acc.x = fmaf(w1, h1.x, acc.x); acc.y = fmaf(w1, h1.y, acc.y);
            acc.z = fmaf(w1, h1.z, acc.z); acc.w = fmaf(w1, h1.w, acc.w);
            den += w0 + w1;
        }
        if (i < cnt) {
            int   s0 = slds[i];
            float w0 = wlds[i];
            float4 h0 = *(const float4*)&h[(size_t)s0 * 256 + lane * 4];
            acc.x = fmaf(w0, h0.x, acc.x); acc.y = fmaf(w0, h0.y, acc.y);
            acc.z = fmaf(w0, h0.z, acc.z); acc.w = fmaf(w0, h0.w, acc.w);
            den += w0;
        }
    }

    *(float4*)&red[w][lane * 4] = acc;
    if (lane == 0) dred[w] = den;
    __syncthreads();

    float v  = red[0][tid] + red[1][tid] + red[2][tid] + red[3][tid];
    float dn = dred[0] + dred[1] + dred[2] + dred[3];
    v = v / dn + bias[tid];
    out[(size_t)n * 256 + tid] = (EPI == 1) ? gelu_exact(v) : fmaxf(v, 0.f);
}

extern "C" void kernel_launch(void* const* d_in, const int* in_sizes, int n_in,
                              void* d_out, int out_size, void* d_ws, size_t ws_size,
                              hipStream_t stream)
{
    const float* img    = (const float*)d_in[0];
    const float* txt    = (const float*)d_in[1];
    const int*   ci     = (const int*)d_in[2];
    const int*   edges  = (const int*)d_in[3];
    const float* w_img  = (const float*)d_in[4];
    const float* b_img  = (const float*)d_in[5];
    const float* w_text = (const float*)d_in[6];
    const float* b_text = (const float*)d_in[7];
    const float* W0     = (const float*)d_in[8];
    const float* asrc0  = (const float*)d_in[9];
    const float* adst0  = (const float*)d_in[10];
    const float* bias0  = (const float*)d_in[11];
    const float* W1     = (const float*)d_in[12];
    const float* asrc1  = (const float*)d_in[13];
    const float* adst1  = (const float*)d_in[14];
    const float* bias1  = (const float*)d_in[15];

    const int N = in_sizes[2];
    const int E = in_sizes[3] / 2;
    const int T = E + N;

    float* fA   = (float*)d_ws;                    // node, later h1   N*256
    float* fB   = fA + (size_t)N * 256;            // out0             N*256
    float* sS   = fB + (size_t)N * 256;            // N
    float* sD   = sS + N;                          // N
    int*   rs   = (int*)(sD + N);                  // N+1
    int*   cur  = rs + (N + 1);                    // N
    int*   col  = cur + N;                         // E+N
    int*   bsum = col + T;                         // <=256
    uintptr_t bt0 = ((uintptr_t)(bsum + 256) + 63) & ~(uintptr_t)63;
    ushort* BtImg = (ushort*)bt0;                  // 128 x 1536
    ushort* BtTxt = BtImg + 128 * 1536;            // 128 x 1536
    ushort* BtW0  = BtTxt + 128 * 1536;            // 256 x 512
    ushort* BtW1  = BtW0  + 256 * 512;             // 256 x 512
    float* h0   = (float*)d_out;                   // N*256 scratch

    const int nb256 = (N + 255) / 256;
    const int nbT   = (T + 255) / 256;
    const int gm64  = (N + 63) / 64;               // 782

    conv_wt<<<(128 * 192 + 255) / 256, 256, 0, stream>>>(w_img,  BtImg, 768, 128);
    conv_wt<<<(128 * 192 + 255) / 256, 256, 0, stream>>>(w_text, BtTxt, 768, 128);
    conv_wt<<<(256 * 64  + 255) / 256, 256, 0, stream>>>(W0,     BtW0,  256, 256);
    conv_wt<<<(256 * 64  + 255) / 256, 256, 0, stream>>>(W1,     BtW1,  256, 256);

    hipMemsetAsync(fA, 0, (size_t)N * 256 * sizeof(float), stream);

    // merged upscale GEMMs: grid (782, 2), y selects img/text set
    gemm64<1><<<dim3(gm64, 2), 256, 0, stream>>>(
        img, txt, BtImg, BtTxt, b_img, b_text, fA, ci, N, 768, 0, 128);

    init_cnt<<<nb256, 256, 0, stream>>>(cur, N);
    count_edges<<<(E + 255) / 256, 256, 0, stream>>>(edges, cur, E);
    scan1<<<nb256, 256, 0, stream>>>(cur, rs, bsum, N);
    scan2<<<1, 256, 0, stream>>>(bsum, nb256);
    scan3<<<nb256, 256, 0, stream>>>(rs, bsum, N, T);
    copy_cursor<<<nb256, 256, 0, stream>>>(rs, cur, N);
    fill_csr<<<nbT, 256, 0, stream>>>(edges, cur, col, E, N);

    // ---- layer 0 ----
    gemm64<0><<<dim3(gm64, 2), 256, 0, stream>>>(
        fA, nullptr, BtW0, nullptr, nullptr, nullptr, h0, nullptr, N, 256, 0, 0);
    scores_kernel<<<(N + 3) / 4, 256, 0, stream>>>(h0, asrc0, adst0, sS, sD, N);
    attn_kernel<0><<<N, 256, 0, stream>>>(h0, sS, sD, rs, col, bias0, fB, N);

    // ---- layer 1 ----
    gemm64<0><<<dim3(gm64, 2), 256, 0, stream>>>(
        fB, nullptr, BtW1, nullptr, nullptr, nullptr, fA, nullptr, N, 256, 0, 0);
    scores_kernel<<<(N + 3) / 4, 256, 0, stream>>>(fA, asrc1, adst1, sS, sD, N);
    attn_kernel<1><<<N, 256, 0, stream>>>(fA, sS, sD, rs, col, bias1, (float*)d_out, N);
}

// Round 6
// 585.114 us; speedup vs baseline: 1.8713x; 1.1334x over previous
//
#include <hip/hip_runtime.h>
#include <math.h>

// ---------------------------------------------------------------------------
// GraphConv (2-layer GAT) pipeline.
// GEMMs: split-bf16 MFMA (fp32 = hi+lo bf16 RNE pair along K, K'=2K).
// R6: latency fix for gemm64 — R5 had loads consumed by a barrier in the SAME
//   K-step (all pipes <15% busy). Now: double-buffered LDS (one barrier/step,
//   inputs issued one step early), B staged via global_load_lds from a
//   PRE-SWIZZLED global tile layout (conv_wt bakes the XOR swizzle), A-regs
//   load-early/convert-late. Attn: 4 rows in flight per wave (was 2).
// ---------------------------------------------------------------------------

typedef __attribute__((ext_vector_type(8))) short bf16x8;
typedef __attribute__((ext_vector_type(4))) float f32x4;

__device__ __forceinline__ float gelu_exact(float x) {
    return 0.5f * x * (1.0f + erff(x * 0.70710678118654752f));
}

// round-to-nearest-even bf16; returns the f32 bit pattern of the rounded value
__device__ __forceinline__ unsigned int rne_bf16_bits(float f) {
    unsigned int u = __float_as_uint(f);
    unsigned int r = u + 0x7FFFu + ((u >> 16) & 1u);
    return r & 0xFFFF0000u;
}

// fp32 -> packed (hi bf16 | lo bf16<<16), RNE split.
__device__ __forceinline__ unsigned int packsplit(float f) {
    unsigned int hi_bits = rne_bf16_bits(f);
    float resid = f - __uint_as_float(hi_bits);
    unsigned int lo_bits = rne_bf16_bits(resid);
    return (hi_bits >> 16) | lo_bits;
}

// ---------------------------------------------------------------------------
// conv_wt: W[K][Bcols] fp32 -> Bt tiles. Tile (ct,kstep) is 8192 ushorts
// holding cols ct*128..+127 x 32 k-values as hi/lo bf16 pairs, ALREADY in the
// swizzled LDS image: tile[col*64 + ((kg*8) ^ ((col&7)<<3)) + j]. gemm64 then
// copies a tile linearly with global_load_lds (dest = base + lane*16).
// ---------------------------------------------------------------------------
__global__ void conv_wt(const float* __restrict__ W, ushort* __restrict__ Bt,
                        int K, int Bcols)
{
    int t = blockIdx.x * 256 + threadIdx.x;
    int KS = K >> 5;
    int total = (Bcols >> 7) * KS * 1024;       // (ct) x (kstep) x (col x kg)
    if (t >= total) return;
    int kg    = t & 7;
    int col   = (t >> 3) & 127;
    int rest  = t >> 10;
    int kstep = rest % KS;
    int ct    = rest / KS;
    int gcol  = ct * 128 + col;
    int kbase = kstep * 32 + kg * 4;
    uint4 v;
    v.x = packsplit(W[(size_t)(kbase + 0) * Bcols + gcol]);
    v.y = packsplit(W[(size_t)(kbase + 1) * Bcols + gcol]);
    v.z = packsplit(W[(size_t)(kbase + 2) * Bcols + gcol]);
    v.w = packsplit(W[(size_t)(kbase + 3) * Bcols + gcol]);
    size_t tile = (size_t)(ct * KS + kstep) * 8192;
    *(uint4*)&Bt[tile + col * 64 + ((kg * 8) ^ ((col & 7) << 3))] = v;
}

// ---------------------------------------------------------------------------
// Split-bf16 MFMA GEMM, tile 64x128, 4 waves (2x2 of 32x64), double-buffered.
// MODE=0 (layer): blockIdx.y = column-tile ct; C[row*256 + ct*128 + col]=acc.
// MODE=1 (upscale): blockIdx.y selects {A0,B0,bias0,cb0}/{A1,B1,bias1,cb1};
//                   C[ci[row]*256 + cb + col] = gelu(acc + bias[col]).
// ---------------------------------------------------------------------------
template<int MODE>
__global__ __launch_bounds__(256)
void gemm64(const float* __restrict__ A0, const float* __restrict__ A1,
            const ushort* __restrict__ B0, const ushort* __restrict__ B1,
            const float* __restrict__ bias0, const float* __restrict__ bias1,
            float* __restrict__ C, const int* __restrict__ ci,
            int M, int K, int cb0, int cb1)
{
    __shared__ ushort As[2][64 * 64];     // 8KB per buffer
    __shared__ ushort Bs[2][128 * 64];    // 16KB per buffer

    const int tid  = threadIdx.x;
    const int lane = tid & 63;
    const int w    = tid >> 6;
    const int wr   = w >> 1, wc = w & 1;
    const int row0 = blockIdx.x * 64;
    const int KS   = K >> 5;

    const float* A; const ushort* Btile; const float* bias; int col_base, colt;
    if (MODE == 1) {
        int sel = blockIdx.y;
        A = sel ? A1 : A0; Btile = sel ? B1 : B0;
        bias = sel ? bias1 : bias0; col_base = sel ? cb1 : cb0; colt = 0;
    } else {
        A = A0; Btile = B0 + (size_t)blockIdx.y * KS * 8192;
        bias = nullptr; col_base = 0; colt = blockIdx.y * 128;
    }

    const int ar0 = tid >> 3;             // A row (p=0): 0..31
    const int ac4 = (tid & 7) * 4;        // A fp32 col within step

    f32x4 acc[2][4];
#pragma unroll
    for (int m = 0; m < 2; m++)
#pragma unroll
        for (int n = 0; n < 4; n++) acc[m][n] = (f32x4)0.f;

    auto loadA = [&](float4* rg, int ks) {
#pragma unroll
        for (int p = 0; p < 2; p++) {
            int gr = row0 + ar0 + p * 32;
            rg[p] = make_float4(0.f, 0.f, 0.f, 0.f);
            if (gr < M) rg[p] = *(const float4*)&A[(size_t)gr * K + ks * 32 + ac4];
        }
    };
    auto writeA = [&](int buf, const float4* rg) {
#pragma unroll
        for (int p = 0; p < 2; p++) {
            int r = ar0 + p * 32;
            uint4 wv;
            wv.x = packsplit(rg[p].x); wv.y = packsplit(rg[p].y);
            wv.z = packsplit(rg[p].z); wv.w = packsplit(rg[p].w);
            *(uint4*)&As[buf][r * 64 + ((2 * ac4) ^ ((r & 7) << 3))] = wv;
        }
    };
    auto stageB = [&](int buf, int ks) {
        const ushort* tp = Btile + (size_t)ks * 8192;
#pragma unroll
        for (int q = 0; q < 4; q++) {
            int off = (w * 4 + q) * 512;          // ushorts; 1KB per call
            __builtin_amdgcn_global_load_lds(
                (const __attribute__((address_space(1))) void*)(tp + off + lane * 8),
                (__attribute__((address_space(3))) void*)(&Bs[buf][off]),
                16, 0, 0);
        }
    };
    auto compute = [&](int buf) {
        bf16x8 af[2][2], bfr[4][2];
#pragma unroll
        for (int m = 0; m < 2; m++) {
            int row = wr * 32 + m * 16 + (lane & 15);
#pragma unroll
            for (int kb = 0; kb < 2; kb++) {
                int kp = kb * 32 + (lane >> 4) * 8;
                af[m][kb] = *(const bf16x8*)&As[buf][row * 64 + (kp ^ ((row & 7) << 3))];
            }
        }
#pragma unroll
        for (int n = 0; n < 4; n++) {
            int cq = wc * 64 + n * 16 + (lane & 15);
#pragma unroll
            for (int kb = 0; kb < 2; kb++) {
                int kp = kb * 32 + (lane >> 4) * 8;
                bfr[n][kb] = *(const bf16x8*)&Bs[buf][cq * 64 + (kp ^ ((cq & 7) << 3))];
            }
        }
#pragma unroll
        for (int m = 0; m < 2; m++)
#pragma unroll
            for (int n = 0; n < 4; n++) {
                acc[m][n] = __builtin_amdgcn_mfma_f32_16x16x32_bf16(
                    af[m][0], bfr[n][0], acc[m][n], 0, 0, 0);
                acc[m][n] = __builtin_amdgcn_mfma_f32_16x16x32_bf16(
                    af[m][1], bfr[n][1], acc[m][n], 0, 0, 0);
            }
    };

    // prologue: fill buffer 0, issue k=1 A loads
    float4 aprev[2];
    loadA(aprev, 0);
    stageB(0, 0);
    writeA(0, aprev);
    if (KS > 1) loadA(aprev, 1);
    __syncthreads();

    int cur = 0;
    for (int ks = 0; ks < KS - 1; ++ks) {
        int nxt = cur ^ 1;
        stageB(nxt, ks + 1);                  // async B into other buffer
        float4 anew[2];
        if (ks + 2 < KS) loadA(anew, ks + 2); // issue A two steps ahead
        writeA(nxt, aprev);                   // convert+write k+1 (regs arrived)
        compute(cur);                         // ds_read + 16 MFMA on current
        __syncthreads();
        aprev[0] = anew[0]; aprev[1] = anew[1];
        cur = nxt;
    }
    compute(cur);

    // epilogue: C/D layout col=lane&15, row=(lane>>4)*4+reg
#pragma unroll
    for (int m = 0; m < 2; m++) {
        int rbase = row0 + wr * 32 + m * 16 + ((lane >> 4) << 2);
#pragma unroll
        for (int n = 0; n < 4; n++) {
            int col = wc * 64 + n * 16 + (lane & 15);
#pragma unroll
            for (int j = 0; j < 4; j++) {
                int grow = rbase + j;
                if (grow >= M) continue;
                float v = acc[m][n][j];
                if (MODE == 1) {
                    v = gelu_exact(v + bias[col]);
                    C[(size_t)ci[grow] * 256 + col_base + col] = v;
                } else {
                    C[(size_t)grow * 256 + colt + col] = v;
                }
            }
        }
    }
}

// per-node attention scores
__global__ __launch_bounds__(256)
void scores_kernel(const float* __restrict__ h, const float* __restrict__ asrc,
                   const float* __restrict__ adst, float* __restrict__ s_src,
                   float* __restrict__ s_dst, int N)
{
    int wave = threadIdx.x >> 6;
    int lane = threadIdx.x & 63;
    int n = blockIdx.x * 4 + wave;
    if (n >= N) return;
    float4 hv = *(const float4*)&h[(size_t)n * 256 + lane * 4];
    float4 av = *(const float4*)&asrc[lane * 4];
    float4 dv = *(const float4*)&adst[lane * 4];
    float ps = hv.x * av.x + hv.y * av.y + hv.z * av.z + hv.w * av.w;
    float pd = hv.x * dv.x + hv.y * dv.y + hv.z * dv.z + hv.w * dv.w;
#pragma unroll
    for (int off = 32; off; off >>= 1) {
        ps += __shfl_xor(ps, off);
        pd += __shfl_xor(pd, off);
    }
    if (lane == 0) { s_src[n] = ps; s_dst[n] = pd; }
}

// ---- CSR build ----
__global__ void init_cnt(int* cnt, int N) {
    int i = blockIdx.x * 256 + threadIdx.x;
    if (i < N) cnt[i] = 1;
}

__global__ void count_edges(const int* __restrict__ edges, int* cnt, int E) {
    int e = blockIdx.x * 256 + threadIdx.x;
    if (e < E) atomicAdd(&cnt[edges[2 * e + 1]], 1);
}

__global__ void scan1(const int* __restrict__ cnt, int* __restrict__ rs,
                      int* __restrict__ bsum, int N)
{
    __shared__ int sm[256];
    int tid = threadIdx.x;
    int i = blockIdx.x * 256 + tid;
    int v = (i < N) ? cnt[i] : 0;
    sm[tid] = v;
    __syncthreads();
    for (int off = 1; off < 256; off <<= 1) {
        int t = (tid >= off) ? sm[tid - off] : 0;
        __syncthreads();
        sm[tid] += t;
        __syncthreads();
    }
    if (i < N) rs[i] = sm[tid] - v;
    if (tid == 255) bsum[blockIdx.x] = sm[255];
}

__global__ void scan2(int* bsum, int nb) {
    __shared__ int sm[256];
    int tid = threadIdx.x;
    int v = (tid < nb) ? bsum[tid] : 0;
    sm[tid] = v;
    __syncthreads();
    for (int off = 1; off < 256; off <<= 1) {
        int t = (tid >= off) ? sm[tid - off] : 0;
        __syncthreads();
        sm[tid] += t;
        __syncthreads();
    }
    if (tid < nb) bsum[tid] = sm[tid] - v;
}

__global__ void scan3(int* __restrict__ rs, const int* __restrict__ bsum,
                      int N, int total)
{
    int i = blockIdx.x * 256 + threadIdx.x;
    if (i < N) rs[i] += bsum[i >> 8];
    if (i == 0) rs[N] = total;
}

__global__ void copy_cursor(const int* __restrict__ rs, int* __restrict__ cur, int N) {
    int i = blockIdx.x * 256 + threadIdx.x;
    if (i < N) cur[i] = rs[i];
}

__global__ void fill_csr(const int* __restrict__ edges, int* __restrict__ cur,
                         int* __restrict__ col, int E, int N)
{
    int i = blockIdx.x * 256 + threadIdx.x;
    if (i < E) {
        int s = edges[2 * i], d = edges[2 * i + 1];
        col[atomicAdd(&cur[d], 1)] = s;
    } else if (i < E + N) {
        int n = i - E;
        col[atomicAdd(&cur[n], 1)] = n;
    }
}

// ---------------------------------------------------------------------------
// attn: block per dst node, 2-phase; phase 2 keeps 4 h-rows in flight per wave.
// ---------------------------------------------------------------------------
template<int EPI>
__global__ __launch_bounds__(256)
void attn_kernel(const float* __restrict__ h, const float* __restrict__ s_src,
                 const float* __restrict__ s_dst, const int* __restrict__ rs,
                 const int* __restrict__ colv, const float* __restrict__ bias,
                 float* __restrict__ out, int N)
{
    __shared__ float wlds[256];
    __shared__ int   slds[256];
    __shared__ float red[4][256];
    __shared__ float dred[4];

    const int n    = blockIdx.x;
    const int tid  = threadIdx.x;
    const int w    = tid >> 6;
    const int lane = tid & 63;

    const float sd = s_dst[n];
    const int beg = rs[n], end = rs[n + 1];

    float4 acc = make_float4(0.f, 0.f, 0.f, 0.f);
    float den = 0.f;

    for (int c0 = beg; c0 < end; c0 += 256) {
        const int cnt = min(256, end - c0);
        __syncthreads();
        if (tid < cnt) {
            int src = colv[c0 + tid];
            float e = s_src[src] + sd;
            e = (e > 0.f) ? e : 0.2f * e;
            wlds[tid] = __expf(e);
            slds[tid] = src;
        }
        __syncthreads();

        int i = w;
        for (; i + 12 < cnt; i += 16) {        // 4 edges/wave/iter in flight
            int   s0 = slds[i],      s1 = slds[i + 4];
            int   s2 = slds[i + 8],  s3 = slds[i + 12];
            float w0 = wlds[i],      w1 = wlds[i + 4];
            float w2 = wlds[i + 8],  w3 = wlds[i + 12];
            float4 h0 = *(const float4*)&h[(size_t)s0 * 256 + lane * 4];
            float4 h1 = *(const float4*)&h[(size_t)s1 * 256 + lane * 4];
            float4 h2 = *(const float4*)&h[(size_t)s2 * 256 + lane * 4];
            float4 h3 = *(const float4*)&h[(size_t)s3 * 256 + lane * 4];
            acc.x = fmaf(w0, h0.x, acc.x); acc.y = fmaf(w0, h0.y, acc.y);
            acc.z = fmaf(w0, h0.z, acc.z); acc.w = fmaf(w0, h0.w, acc.w);
            acc.x = fmaf(w1, h1.x, acc.x); acc.y = fmaf(w1, h1.y, acc.y);
            acc.z = fmaf(w1, h1.z, acc.z); acc.w = fmaf(w1, h1.w, acc.w);
            acc.x = fmaf(w2, h2.x, acc.x); acc.y = fmaf(w2, h2.y, acc.y);
            acc.z = fmaf(w2, h2.z, acc.z); acc.w = fmaf(w2, h2.w, acc.w);
            acc.x = fmaf(w3, h3.x, acc.x); acc.y = fmaf(w3, h3.y, acc.y);
            acc.z = fmaf(w3, h3.z, acc.z); acc.w = fmaf(w3, h3.w, acc.w);
            den += w0 + w1 + w2 + w3;
        }
        for (; i < cnt; i += 4) {
            int   s0 = slds[i];
            float w0 = wlds[i];
            float4 h0 = *(const float4*)&h[(size_t)s0 * 256 + lane * 4];
            acc.x = fmaf(w0, h0.x, acc.x); acc.y = fmaf(w0, h0.y, acc.y);
            acc.z = fmaf(w0, h0.z, acc.z); acc.w = fmaf(w0, h0.w, acc.w);
            den += w0;
        }
    }

    *(float4*)&red[w][lane * 4] = acc;
    if (lane == 0) dred[w] = den;
    __syncthreads();

    float v  = red[0][tid] + red[1][tid] + red[2][tid] + red[3][tid];
    float dn = dred[0] + dred[1] + dred[2] + dred[3];
    v = v / dn + bias[tid];
    out[(size_t)n * 256 + tid] = (EPI == 1) ? gelu_exact(v) : fmaxf(v, 0.f);
}

extern "C" void kernel_launch(void* const* d_in, const int* in_sizes, int n_in,
                              void* d_out, int out_size, void* d_ws, size_t ws_size,
                              hipStream_t stream)
{
    const float* img    = (const float*)d_in[0];
    const float* txt    = (const float*)d_in[1];
    const int*   ci     = (const int*)d_in[2];
    const int*   edges  = (const int*)d_in[3];
    const float* w_img  = (const float*)d_in[4];
    const float* b_img  = (const float*)d_in[5];
    const float* w_text = (const float*)d_in[6];
    const float* b_text = (const float*)d_in[7];
    const float* W0     = (const float*)d_in[8];
    const float* asrc0  = (const float*)d_in[9];
    const float* adst0  = (const float*)d_in[10];
    const float* bias0  = (const float*)d_in[11];
    const float* W1     = (const float*)d_in[12];
    const float* asrc1  = (const float*)d_in[13];
    const float* adst1  = (const float*)d_in[14];
    const float* bias1  = (const float*)d_in[15];

    const int N = in_sizes[2];
    const int E = in_sizes[3] / 2;
    const int T = E + N;

    float* fA   = (float*)d_ws;                    // node, later h1   N*256
    float* fB   = fA + (size_t)N * 256;            // out0             N*256
    float* sS   = fB + (size_t)N * 256;            // N
    float* sD   = sS + N;                          // N
    int*   rs   = (int*)(sD + N);                  // N+1
    int*   cur  = rs + (N + 1);                    // N
    int*   col  = cur + N;                         // E+N
    int*   bsum = col + T;                         // <=256
    uintptr_t bt0 = ((uintptr_t)(bsum + 256) + 63) & ~(uintptr_t)63;
    ushort* BtImg = (ushort*)bt0;                  // 24 tiles x 8192
    ushort* BtTxt = BtImg + 24 * 8192;             // 24 tiles x 8192
    ushort* BtW0  = BtTxt + 24 * 8192;             // 16 tiles x 8192
    ushort* BtW1  = BtW0  + 16 * 8192;             // 16 tiles x 8192
    float* h0   = (float*)d_out;                   // N*256 scratch

    const int nb256 = (N + 255) / 256;
    const int nbT   = (T + 255) / 256;
    const int gm64  = (N + 63) / 64;               // 782

    // weight pre-conversion into pre-swizzled tile layout
    conv_wt<<<(1 * 24 * 1024 + 255) / 256, 256, 0, stream>>>(w_img,  BtImg, 768, 128);
    conv_wt<<<(1 * 24 * 1024 + 255) / 256, 256, 0, stream>>>(w_text, BtTxt, 768, 128);
    conv_wt<<<(2 * 8  * 1024 + 255) / 256, 256, 0, stream>>>(W0,     BtW0,  256, 256);
    conv_wt<<<(2 * 8  * 1024 + 255) / 256, 256, 0, stream>>>(W1,     BtW1,  256, 256);

    // merged upscale GEMMs: grid (782, 2), y selects img/text set.
    // (no memset: ci is a permutation covering all rows; both halves write
    //  all 256 cols)
    gemm64<1><<<dim3(gm64, 2), 256, 0, stream>>>(
        img, txt, BtImg, BtTxt, b_img, b_text, fA, ci, N, 768, 0, 128);

    init_cnt<<<nb256, 256, 0, stream>>>(cur, N);
    count_edges<<<(E + 255) / 256, 256, 0, stream>>>(edges, cur, E);
    scan1<<<nb256, 256, 0, stream>>>(cur, rs, bsum, N);
    scan2<<<1, 256, 0, stream>>>(bsum, nb256);
    scan3<<<nb256, 256, 0, stream>>>(rs, bsum, N, T);
    copy_cursor<<<nb256, 256, 0, stream>>>(rs, cur, N);
    fill_csr<<<nbT, 256, 0, stream>>>(edges, cur, col, E, N);

    // ---- layer 0 ----
    gemm64<0><<<dim3(gm64, 2), 256, 0, stream>>>(
        fA, nullptr, BtW0, nullptr, nullptr, nullptr, h0, nullptr, N, 256, 0, 0);
    scores_kernel<<<(N + 3) / 4, 256, 0, stream>>>(h0, asrc0, adst0, sS, sD, N);
    attn_kernel<0><<<N, 256, 0, stream>>>(h0, sS, sD, rs, col, bias0, fB, N);

    // ---- layer 1 ----
    gemm64<0><<<dim3(gm64, 2), 256, 0, stream>>>(
        fB, nullptr, BtW1, nullptr, nullptr, nullptr, fA, nullptr, N, 256, 0, 0);
    scores_kernel<<<(N + 3) / 4, 256, 0, stream>>>(fA, asrc1, adst1, sS, sD, N);
    attn_kernel<1><<<N, 256, 0, stream>>>(fA, sS, sD, rs, col, bias1, (float*)d_out, N);
}